// Round 3
// baseline (601.036 us; speedup 1.0000x reference)
//
#include <hip/hip_runtime.h>

static constexpr int kNE = 50000;
static constexpr int kNR = 1000;
static constexpr int kE  = 800000;
static constexpr int kEH = 256;
static constexpr int kRH = 64;
static constexpr float kNeg = 0.01f;

__device__ __forceinline__ float lrelu(float x){ return x > 0.f ? x : kNeg * x; }

// float atomic-max via int max / uint min; correct given -inf init.
__device__ __forceinline__ void atomicMaxF(float* addr, float val){
    if (val >= 0.f) atomicMax((int*)addr, __float_as_int(val));
    else            atomicMin((unsigned int*)addr, __float_as_uint(val));
}

__global__ void k_init(float* m_h, float* m_t, float* d_h, float* d_t, float* out){
    int i = blockIdx.x * blockDim.x + threadIdx.x;
    int stride = gridDim.x * blockDim.x;
    for (int j = i; j < kNE * 2 * kRH; j += stride) out[j] = 0.f;
    for (int j = i; j < kNE; j += stride){
        m_h[j] = -INFINITY; m_t[j] = -INFINITY;
        d_h[j] = 0.f;       d_t[j] = 0.f;
    }
}

// one wave per node: 256 dims, float4 per lane, dual dot + shuffle reduce
__global__ void k_node_scores(const float* __restrict__ xe, const float* __restrict__ ahw,
                              const float* __restrict__ atw, float* s_h, float* s_t){
    int gid  = blockIdx.x * blockDim.x + threadIdx.x;
    int node = gid >> 6;
    int lane = threadIdx.x & 63;
    if (node >= kNE) return;
    const float4* row = (const float4*)(xe + (size_t)node * kEH);
    float4 xv = row[lane];
    float4 av = ((const float4*)ahw)[lane];
    float4 bv = ((const float4*)atw)[lane];
    float ph = xv.x*av.x + xv.y*av.y + xv.z*av.z + xv.w*av.w;
    float pt = xv.x*bv.x + xv.y*bv.y + xv.z*bv.z + xv.w*bv.w;
    #pragma unroll
    for (int off = 32; off > 0; off >>= 1){
        ph += __shfl_down(ph, off, 64);
        pt += __shfl_down(pt, off, 64);
    }
    if (lane == 0){ s_h[node] = ph; s_t[node] = pt; }
}

// one wave per relation: 64 dims, 1 per lane
__global__ void k_rel_scores(const float* __restrict__ xr, const float* __restrict__ arw,
                             float* s_r){
    int gid = blockIdx.x * blockDim.x + threadIdx.x;
    int r   = gid >> 6;
    int lane = threadIdx.x & 63;
    if (r >= kNR) return;
    float p = xr[(size_t)r * kRH + lane] * arw[lane];
    #pragma unroll
    for (int off = 32; off > 0; off >>= 1) p += __shfl_down(p, off, 64);
    if (lane == 0) s_r[r] = p;
}

__global__ void k_edge_logits(const int* __restrict__ head, const int* __restrict__ tail,
                              const int* __restrict__ rel,
                              const float* __restrict__ s_h, const float* __restrict__ s_t,
                              const float* __restrict__ s_r,
                              float* lh_arr, float* lt_arr, float* m_h, float* m_t){
    int i = blockIdx.x * blockDim.x + threadIdx.x;
    if (i >= kE) return;
    int h = head[i], t = tail[i], r = rel[i];
    float sr = s_r[r];
    float lh = lrelu(s_h[h] + sr);
    float lt = lrelu(s_t[t] + sr);
    lh_arr[i] = lh;  lt_arr[i] = lt;
    atomicMaxF(&m_h[h], lh);
    atomicMaxF(&m_t[t], lt);
}

__global__ void k_edge_exp(const int* __restrict__ head, const int* __restrict__ tail,
                           float* lh_arr, float* lt_arr,
                           const float* __restrict__ m_h, const float* __restrict__ m_t,
                           float* d_h, float* d_t){
    int i = blockIdx.x * blockDim.x + threadIdx.x;
    if (i >= kE) return;
    int h = head[i], t = tail[i];
    float eh = expf(lh_arr[i] - m_h[h]);
    float et = expf(lt_arr[i] - m_t[t]);
    lh_arr[i] = eh;  lt_arr[i] = et;
    atomicAdd(&d_h[h], eh);
    atomicAdd(&d_t[t], et);
}

// one wave per edge: lane = feature dim (64), scatter-add alpha * x_r[rel] into d_out
__global__ void k_scatter(const int* __restrict__ head, const int* __restrict__ tail,
                          const int* __restrict__ rel, const float* __restrict__ xr,
                          const float* __restrict__ ex_h, const float* __restrict__ ex_t,
                          const float* __restrict__ d_h, const float* __restrict__ d_t,
                          float* out){
    int gid  = blockIdx.x * blockDim.x + threadIdx.x;
    int e    = gid >> 6;
    int lane = threadIdx.x & 63;
    if (e >= kE) return;
    int h = head[e], t = tail[e], r = rel[e];
    float ah = ex_h[e] / (d_h[h] + 1e-16f);
    float at = ex_t[e] / (d_t[t] + 1e-16f);
    float v  = xr[(size_t)r * kRH + lane];
    atomicAdd(&out[(size_t)h * (2*kRH) + lane],       ah * v);
    atomicAdd(&out[(size_t)t * (2*kRH) + kRH + lane], at * v);
}

extern "C" void kernel_launch(void* const* d_in, const int* in_sizes, int n_in,
                              void* d_out, int out_size, void* d_ws, size_t ws_size,
                              hipStream_t stream) {
    const float* xe  = (const float*)d_in[0];   // [50000,256] f32
    const float* xr  = (const float*)d_in[1];   // [1000,64]   f32
    const int* edge_index = (const int*)d_in[2];// [2,800000]
    const int* rel        = (const int*)d_in[3];// [800000]
    // d_in[4] line_graph_index, d_in[5] line_graph_val: unused by reference
    const float* ahw = (const float*)d_in[6];   // [256] f32
    const float* atw = (const float*)d_in[7];   // [256] f32
    const float* arw = (const float*)d_in[8];   // [64]  f32
    float* out = (float*)d_out;                 // [50000,128] f32

    const int* head = edge_index;
    const int* tail = edge_index + kE;

    float* ws  = (float*)d_ws;
    float* s_h = ws;                 // 50000
    float* s_t = s_h + kNE;          // 50000
    float* s_r = s_t + kNE;          // 1000
    float* m_h = s_r + kNR;          // 50000
    float* m_t = m_h + kNE;          // 50000
    float* d_h = m_t + kNE;          // 50000
    float* d_t = d_h + kNE;          // 50000
    float* lh  = d_t + kNE;          // 800000 (logits -> exp)
    float* lt  = lh + kE;            // 800000

    k_init<<<4096, 256, 0, stream>>>(m_h, m_t, d_h, d_t, out);
    k_node_scores<<<(kNE * 64 + 255) / 256, 256, 0, stream>>>(xe, ahw, atw, s_h, s_t);
    k_rel_scores<<<(kNR * 64 + 255) / 256, 256, 0, stream>>>(xr, arw, s_r);
    k_edge_logits<<<(kE + 255) / 256, 256, 0, stream>>>(head, tail, rel, s_h, s_t, s_r,
                                                        lh, lt, m_h, m_t);
    k_edge_exp<<<(kE + 255) / 256, 256, 0, stream>>>(head, tail, lh, lt, m_h, m_t, d_h, d_t);
    k_scatter<<<(kE * 64 + 255) / 256, 256, 0, stream>>>(head, tail, rel, xr,
                                                         lh, lt, d_h, d_t, out);
}

// Round 4
// 367.613 us; speedup vs baseline: 1.6350x; 1.6350x over previous
//
#include <hip/hip_runtime.h>

static constexpr int kNE = 50000;
static constexpr int kNR = 1000;
static constexpr int kE  = 800000;
static constexpr int kEH = 256;
static constexpr int kRH = 64;
static constexpr float kNeg = 0.01f;

static constexpr int kSegs = 2 * kNE;                 // head segments then tail segments
static constexpr int kNB   = (kSegs + 255) / 256;     // scan blocks = 391

__device__ __forceinline__ float lrelu(float x){ return x > 0.f ? x : kNeg * x; }

__global__ void k_init(int* cnt, int* fill){
    int i = blockIdx.x * blockDim.x + threadIdx.x;
    int stride = gridDim.x * blockDim.x;
    for (int j = i; j < kSegs; j += stride){ cnt[j] = 0; fill[j] = 0; }
}

// one wave per node: 256 dims, float4 per lane, dual dot + shuffle reduce
__global__ void k_node_scores(const float* __restrict__ xe, const float* __restrict__ ahw,
                              const float* __restrict__ atw, float* s_h, float* s_t){
    int gid  = blockIdx.x * blockDim.x + threadIdx.x;
    int node = gid >> 6;
    int lane = threadIdx.x & 63;
    if (node >= kNE) return;
    const float4* row = (const float4*)(xe + (size_t)node * kEH);
    float4 xv = row[lane];
    float4 av = ((const float4*)ahw)[lane];
    float4 bv = ((const float4*)atw)[lane];
    float ph = xv.x*av.x + xv.y*av.y + xv.z*av.z + xv.w*av.w;
    float pt = xv.x*bv.x + xv.y*bv.y + xv.z*bv.z + xv.w*bv.w;
    #pragma unroll
    for (int off = 32; off > 0; off >>= 1){
        ph += __shfl_down(ph, off, 64);
        pt += __shfl_down(pt, off, 64);
    }
    if (lane == 0){ s_h[node] = ph; s_t[node] = pt; }
}

// one wave per relation: 64 dims, 1 per lane
__global__ void k_rel_scores(const float* __restrict__ xr, const float* __restrict__ arw,
                             float* s_r){
    int gid = blockIdx.x * blockDim.x + threadIdx.x;
    int r   = gid >> 6;
    int lane = threadIdx.x & 63;
    if (r >= kNR) return;
    float p = xr[(size_t)r * kRH + lane] * arw[lane];
    #pragma unroll
    for (int off = 32; off > 0; off >>= 1) p += __shfl_down(p, off, 64);
    if (lane == 0) s_r[r] = p;
}

// count edges per (head) segment and per (tail) segment
__global__ void k_count(const int* __restrict__ head, const int* __restrict__ tail, int* cnt){
    int i = blockIdx.x * blockDim.x + threadIdx.x;
    if (i >= kE) return;
    atomicAdd(&cnt[head[i]], 1);
    atomicAdd(&cnt[kNE + tail[i]], 1);
}

// exclusive scan over cnt[kSegs] -> off, 3-kernel two-level scan
__global__ void k_scan1(const int* __restrict__ cnt, int* __restrict__ off, int* __restrict__ bsum){
    __shared__ int sh[256];
    int tid = threadIdx.x;
    int i = blockIdx.x * 256 + tid;
    int v = (i < kSegs) ? cnt[i] : 0;
    int x = v;
    sh[tid] = x; __syncthreads();
    for (int o = 1; o < 256; o <<= 1){
        int t = (tid >= o) ? sh[tid - o] : 0;
        __syncthreads();
        x += t; sh[tid] = x;
        __syncthreads();
    }
    if (i < kSegs) off[i] = x - v;          // exclusive within block
    if (tid == 255) bsum[blockIdx.x] = x;   // block total
}

__global__ void k_scan2(const int* __restrict__ bsum, int* __restrict__ boff){
    __shared__ int sh[512];
    int tid = threadIdx.x;
    int v = (tid < kNB) ? bsum[tid] : 0;
    int x = v;
    sh[tid] = x; __syncthreads();
    for (int o = 1; o < 512; o <<= 1){
        int t = (tid >= o) ? sh[tid - o] : 0;
        __syncthreads();
        x += t; sh[tid] = x;
        __syncthreads();
    }
    if (tid < kNB) boff[tid] = x - v;       // exclusive block offsets
}

__global__ void k_scan3(int* __restrict__ off, const int* __restrict__ boff){
    int i = blockIdx.x * 256 + threadIdx.x;
    if (i < kSegs) off[i] += boff[blockIdx.x];
    if (i == 0) off[kSegs] = 2 * kE;
}

// scatter edge ids into CSR buckets
__global__ void k_fill(const int* __restrict__ head, const int* __restrict__ tail,
                       const int* __restrict__ off, int* __restrict__ fill,
                       int* __restrict__ eids){
    int i = blockIdx.x * blockDim.x + threadIdx.x;
    if (i >= kE) return;
    int h = head[i];
    int p = atomicAdd(&fill[h], 1);
    eids[off[h] + p] = i;
    int t = kNE + tail[i];
    int q = atomicAdd(&fill[t], 1);
    eids[off[t] + q] = i;
}

// one wave per segment: softmax over its edges + aggregate x_r[rel]; no atomics.
__global__ void k_aggregate(const int* __restrict__ off, const int* __restrict__ eids,
                            const int* __restrict__ rel, const float* __restrict__ xr,
                            const float* __restrict__ s_h, const float* __restrict__ s_t,
                            const float* __restrict__ s_r, float* __restrict__ out){
    int gid  = blockIdx.x * blockDim.x + threadIdx.x;
    int seg  = gid >> 6;
    int lane = threadIdx.x & 63;
    if (seg >= kSegs) return;
    bool isHead = seg < kNE;
    int node = isHead ? seg : seg - kNE;
    int base = off[seg];
    int end  = off[seg + 1];
    int deg  = end - base;
    float sn = isHead ? s_h[node] : s_t[node];

    // pass 1: segment max (cache chunk-0 logit+rel in registers; deg<=64 is the common case)
    float lg0 = -INFINITY; int r0 = 0;
    float mloc = -INFINITY;
    for (int c = 0; c < deg; c += 64){
        int k = c + lane;
        float lg = -INFINITY; int rr = 0;
        if (k < deg){
            int e = eids[base + k];
            rr = rel[e];
            lg = lrelu(sn + s_r[rr]);
        }
        if (c == 0){ lg0 = lg; r0 = rr; }
        mloc = fmaxf(mloc, lg);
    }
    #pragma unroll
    for (int o = 32; o > 0; o >>= 1) mloc = fmaxf(mloc, __shfl_xor(mloc, o, 64));
    float m = mloc;

    // pass 2: denom
    float sloc = 0.f;
    for (int c = 0; c < deg; c += 64){
        int k = c + lane;
        float lg = lg0;
        if (c != 0){
            lg = -INFINITY;
            if (k < deg){
                int e = eids[base + k];
                lg = lrelu(sn + s_r[rel[e]]);
            }
        }
        if (k < deg) sloc += __expf(lg - m);
    }
    #pragma unroll
    for (int o = 32; o > 0; o >>= 1) sloc += __shfl_xor(sloc, o, 64);
    float inv = 1.f / (sloc + 1e-16f);

    // pass 3: accumulate alpha * x_r[rel] (lane = feature dim)
    float acc = 0.f;
    for (int c = 0; c < deg; c += 64){
        int k = c + lane;
        float a = 0.f; int rr = 0;
        if (c == 0){
            if (k < deg){ a = __expf(lg0 - m) * inv; rr = r0; }
        } else if (k < deg){
            int e = eids[base + k];
            rr = rel[e];
            float lg = lrelu(sn + s_r[rr]);
            a = __expf(lg - m) * inv;
        }
        int cs = min(64, deg - c);
        for (int j = 0; j < cs; ++j){
            float aj = __shfl(a, j, 64);
            int   rj = __shfl(rr, j, 64);
            acc += aj * xr[(size_t)rj * kRH + lane];
        }
    }
    int col = isHead ? lane : (kRH + lane);
    out[(size_t)node * (2 * kRH) + col] = acc;
}

extern "C" void kernel_launch(void* const* d_in, const int* in_sizes, int n_in,
                              void* d_out, int out_size, void* d_ws, size_t ws_size,
                              hipStream_t stream) {
    const float* xe  = (const float*)d_in[0];    // [50000,256] f32
    const float* xr  = (const float*)d_in[1];    // [1000,64]   f32
    const int* edge_index = (const int*)d_in[2]; // [2,800000]
    const int* rel        = (const int*)d_in[3]; // [800000]
    // d_in[4], d_in[5] unused by reference
    const float* ahw = (const float*)d_in[6];    // [256]
    const float* atw = (const float*)d_in[7];    // [256]
    const float* arw = (const float*)d_in[8];    // [64]
    float* out = (float*)d_out;                  // [50000,128] f32

    const int* head = edge_index;
    const int* tail = edge_index + kE;

    char* ws = (char*)d_ws;
    float* s_h  = (float*)ws;                      ws += kNE * sizeof(float);
    float* s_t  = (float*)ws;                      ws += kNE * sizeof(float);
    float* s_r  = (float*)ws;                      ws += kNR * sizeof(float);
    int*   cnt  = (int*)ws;                        ws += kSegs * sizeof(int);
    int*   off  = (int*)ws;                        ws += (kSegs + 1) * sizeof(int);
    int*   bsum = (int*)ws;                        ws += 512 * sizeof(int);
    int*   boff = (int*)ws;                        ws += 512 * sizeof(int);
    int*   fill = (int*)ws;                        ws += kSegs * sizeof(int);
    int*   eids = (int*)ws;                        ws += 2 * kE * sizeof(int);

    k_init<<<256, 256, 0, stream>>>(cnt, fill);
    k_node_scores<<<(kNE * 64 + 255) / 256, 256, 0, stream>>>(xe, ahw, atw, s_h, s_t);
    k_rel_scores<<<(kNR * 64 + 255) / 256, 256, 0, stream>>>(xr, arw, s_r);
    k_count<<<(kE + 255) / 256, 256, 0, stream>>>(head, tail, cnt);
    k_scan1<<<kNB, 256, 0, stream>>>(cnt, off, bsum);
    k_scan2<<<1, 512, 0, stream>>>(bsum, boff);
    k_scan3<<<kNB, 256, 0, stream>>>(off, boff);
    k_fill<<<(kE + 255) / 256, 256, 0, stream>>>(head, tail, off, fill, eids);
    k_aggregate<<<(kSegs * 64 + 255) / 256, 256, 0, stream>>>(off, eids, rel, xr,
                                                              s_h, s_t, s_r, out);
}

// Round 5
// 256.008 us; speedup vs baseline: 2.3477x; 1.4359x over previous
//
#include <hip/hip_runtime.h>

static constexpr int kNE = 50000;
static constexpr int kNR = 1000;
static constexpr int kE  = 800000;
static constexpr int kEH = 256;
static constexpr int kRH = 64;
static constexpr float kNeg = 0.01f;

static constexpr int kSegs = 2 * kNE;          // head segs [0,50000), tail segs [50000,100000)
static constexpr int kSegsPerB = 128;
static constexpr int kB   = (kSegs + kSegsPerB - 1) / kSegsPerB;   // 782 buckets
static constexpr int kCap = 3072;              // per-bucket record capacity (mean 2047, sd 45)
static constexpr int kEdgesPerBlkA = 2048;
static constexpr int kBlkScoreN = kNE / 4;     // 12500 blocks, wave per node
static constexpr int kBlkScoreR = kNR / 4;     // 250 blocks, wave per rel
static constexpr int kBlkA = (kE + kEdgesPerBlkA - 1) / kEdgesPerBlkA;   // 391

__device__ __forceinline__ float lrelu(float x){ return x > 0.f ? x : kNeg * x; }

// ---------------- K1: node scores + rel scores + binA (grid-sectioned) ----------------
__global__ __launch_bounds__(256) void k_scores_binA(
        const float* __restrict__ xe, const float* __restrict__ ahw,
        const float* __restrict__ atw, const float* __restrict__ xr,
        const float* __restrict__ arw,
        const int* __restrict__ head, const int* __restrict__ tail,
        const int* __restrict__ rel,
        float* __restrict__ s_h, float* __restrict__ s_t, float* __restrict__ s_r,
        int* __restrict__ bucket_fill, unsigned int* __restrict__ records){
    __shared__ int cnt[kB];
    __shared__ int gbase[kB];
    int blk = blockIdx.x;
    int tid = threadIdx.x;
    int lane = tid & 63;

    if (blk < kBlkScoreN){
        // ---- node scores: wave per node, 256 dims = 64 lanes x float4
        int node = blk * 4 + (tid >> 6);
        const float4* row = (const float4*)(xe + (size_t)node * kEH);
        float4 xv = row[lane];
        float4 av = ((const float4*)ahw)[lane];
        float4 bv = ((const float4*)atw)[lane];
        float ph = xv.x*av.x + xv.y*av.y + xv.z*av.z + xv.w*av.w;
        float pt = xv.x*bv.x + xv.y*bv.y + xv.z*bv.z + xv.w*bv.w;
        #pragma unroll
        for (int o = 32; o > 0; o >>= 1){
            ph += __shfl_down(ph, o, 64);
            pt += __shfl_down(pt, o, 64);
        }
        if (lane == 0){ s_h[node] = ph; s_t[node] = pt; }
        return;
    }
    if (blk < kBlkScoreN + kBlkScoreR){
        // ---- rel scores: wave per rel
        int r = (blk - kBlkScoreN) * 4 + (tid >> 6);
        float p = xr[(size_t)r * kRH + lane] * arw[lane];
        #pragma unroll
        for (int o = 32; o > 0; o >>= 1) p += __shfl_down(p, o, 64);
        if (lane == 0) s_r[r] = p;
        return;
    }
    // ---- binA: pack (seg<<10)|rel, bin into kB buckets of 128 segs
    int ab = blk - (kBlkScoreN + kBlkScoreR);
    int e0 = ab * kEdgesPerBlkA;
    for (int i = tid; i < kB; i += 256) cnt[i] = 0;
    __syncthreads();
    unsigned int ra[8], rb[8];
    #pragma unroll
    for (int p = 0; p < 8; ++p){
        int e = e0 + p * 256 + tid;
        unsigned int rh = 0xFFFFFFFFu, rt = 0xFFFFFFFFu;
        if (e < kE){
            int h = head[e], t = tail[e], r = rel[e];
            rh = ((unsigned int)h << 10) | (unsigned int)r;
            rt = ((unsigned int)(kNE + t) << 10) | (unsigned int)r;
            atomicAdd(&cnt[h >> 7], 1);
            atomicAdd(&cnt[(kNE + t) >> 7], 1);
        }
        ra[p] = rh; rb[p] = rt;
    }
    __syncthreads();
    for (int i = tid; i < kB; i += 256){
        int c = cnt[i];
        gbase[i] = (c > 0) ? atomicAdd(&bucket_fill[i], c) : 0;
    }
    __syncthreads();
    #pragma unroll
    for (int p = 0; p < 8; ++p){
        unsigned int rc = ra[p];
        if (rc != 0xFFFFFFFFu){
            int bk = rc >> 17;                      // seg>>7
            int slot = atomicAdd(&gbase[bk], 1);
            if (slot < kCap) records[(size_t)bk * kCap + slot] = rc;
        }
        rc = rb[p];
        if (rc != 0xFFFFFFFFu){
            int bk = rc >> 17;
            int slot = atomicAdd(&gbase[bk], 1);
            if (slot < kCap) records[(size_t)bk * kCap + slot] = rc;
        }
    }
}

// ---------------- K3: per-bucket LDS counting-sort + segment softmax + aggregate ----------------
__global__ __launch_bounds__(256) void k_sort_aggregate(
        const int* __restrict__ bucket_fill, const unsigned int* __restrict__ records,
        const float* __restrict__ s_h, const float* __restrict__ s_t,
        const float* __restrict__ s_r, const float* __restrict__ xr,
        float* __restrict__ out){
    __shared__ float srl[kNR];                 // s_r copy (4 KB)
    __shared__ unsigned short relbuf[kCap];    // sorted rel ids (6 KB)
    __shared__ int cnt[kSegsPerB];
    __shared__ int start[kSegsPerB];
    __shared__ int cur[kSegsPerB];
    __shared__ int scanbuf[kSegsPerB];

    int b = blockIdx.x;
    int tid = threadIdx.x;
    int lane = tid & 63;
    int wave = tid >> 6;

    for (int i = tid; i < kNR; i += 256) srl[i] = s_r[i];
    if (tid < kSegsPerB) cnt[tid] = 0;
    __syncthreads();

    int nrec = bucket_fill[b];
    if (nrec > kCap) nrec = kCap;
    const unsigned int* rb = records + (size_t)b * kCap;

    unsigned int recs[12];
    #pragma unroll
    for (int p = 0; p < 12; ++p){
        int idx = p * 256 + tid;
        unsigned int rc = 0xFFFFFFFFu;
        if (idx < nrec){
            rc = rb[idx];
            atomicAdd(&cnt[(rc >> 10) & 127], 1);
        }
        recs[p] = rc;
    }
    __syncthreads();
    // exclusive scan of cnt -> start
    if (tid < kSegsPerB) scanbuf[tid] = cnt[tid];
    __syncthreads();
    for (int o = 1; o < kSegsPerB; o <<= 1){
        int v = 0;
        if (tid < kSegsPerB && tid >= o) v = scanbuf[tid - o];
        __syncthreads();
        if (tid < kSegsPerB) scanbuf[tid] += v;
        __syncthreads();
    }
    if (tid < kSegsPerB){
        int s = scanbuf[tid] - cnt[tid];
        start[tid] = s;
        cur[tid] = s;
    }
    __syncthreads();
    // scatter rel ids into LDS, grouped by local seg
    #pragma unroll
    for (int p = 0; p < 12; ++p){
        unsigned int rc = recs[p];
        if (rc != 0xFFFFFFFFu){
            int ls = (rc >> 10) & 127;
            int slot = atomicAdd(&cur[ls], 1);
            relbuf[slot] = (unsigned short)(rc & 1023u);
        }
    }
    __syncthreads();

    // aggregate: each wave handles local segs wave, wave+4, ...
    for (int ls = wave; ls < kSegsPerB; ls += 4){
        int gseg = b * kSegsPerB + ls;
        if (gseg >= kSegs) break;
        bool isHead = gseg < kNE;
        int node = isHead ? gseg : gseg - kNE;
        int deg  = cnt[ls];
        int st   = start[ls];
        float sn = isHead ? s_h[node] : s_t[node];

        // pass 1: max (cache chunk-0 logit+rel)
        float lg0 = -INFINITY; int r0 = 0;
        float mloc = -INFINITY;
        for (int c = 0; c < deg; c += 64){
            int k = c + lane;
            float lg = -INFINITY; int rr = 0;
            if (k < deg){
                rr = relbuf[st + k];
                lg = lrelu(sn + srl[rr]);
            }
            if (c == 0){ lg0 = lg; r0 = rr; }
            mloc = fmaxf(mloc, lg);
        }
        #pragma unroll
        for (int o = 32; o > 0; o >>= 1) mloc = fmaxf(mloc, __shfl_xor(mloc, o, 64));
        float m = mloc;

        // pass 2: denom
        float sloc = 0.f;
        for (int c = 0; c < deg; c += 64){
            int k = c + lane;
            float lg = lg0;
            if (c != 0){
                lg = -INFINITY;
                if (k < deg) lg = lrelu(sn + srl[relbuf[st + k]]);
            }
            if (k < deg) sloc += __expf(lg - m);
        }
        #pragma unroll
        for (int o = 32; o > 0; o >>= 1) sloc += __shfl_xor(sloc, o, 64);
        float inv = 1.f / (sloc + 1e-16f);

        // pass 3: acc = sum alpha_e * xr[rel_e][lane]
        float acc = 0.f;
        for (int c = 0; c < deg; c += 64){
            int k = c + lane;
            float a = 0.f; int rr = 0;
            if (c == 0){
                if (k < deg){ a = __expf(lg0 - m) * inv; rr = r0; }
            } else if (k < deg){
                rr = relbuf[st + k];
                a = __expf(lrelu(sn + srl[rr]) - m) * inv;
            }
            int cs = min(64, deg - c);
            for (int j = 0; j < cs; ++j){
                float aj = __shfl(a, j, 64);
                int   rj = __shfl(rr, j, 64);
                acc += aj * xr[(size_t)rj * kRH + lane];
            }
        }
        int col = isHead ? lane : (kRH + lane);
        out[(size_t)node * (2 * kRH) + col] = acc;
    }
}

extern "C" void kernel_launch(void* const* d_in, const int* in_sizes, int n_in,
                              void* d_out, int out_size, void* d_ws, size_t ws_size,
                              hipStream_t stream) {
    const float* xe  = (const float*)d_in[0];    // [50000,256] f32
    const float* xr  = (const float*)d_in[1];    // [1000,64]   f32
    const int* edge_index = (const int*)d_in[2]; // [2,800000]
    const int* rel        = (const int*)d_in[3]; // [800000]
    const float* ahw = (const float*)d_in[6];    // [256]
    const float* atw = (const float*)d_in[7];    // [256]
    const float* arw = (const float*)d_in[8];    // [64]
    float* out = (float*)d_out;                  // [50000,128] f32

    const int* head = edge_index;
    const int* tail = edge_index + kE;

    char* ws = (char*)d_ws;
    float* s_h  = (float*)ws;                    ws += kNE * sizeof(float);
    float* s_t  = (float*)ws;                    ws += kNE * sizeof(float);
    float* s_r  = (float*)ws;                    ws += kNR * sizeof(float);
    int*   bucket_fill = (int*)ws;               ws += kB * sizeof(int);
    unsigned int* records = (unsigned int*)ws;   ws += (size_t)kB * kCap * sizeof(unsigned int);

    hipMemsetAsync(bucket_fill, 0, kB * sizeof(int), stream);
    k_scores_binA<<<kBlkScoreN + kBlkScoreR + kBlkA, 256, 0, stream>>>(
        xe, ahw, atw, xr, arw, head, tail, rel, s_h, s_t, s_r, bucket_fill, records);
    k_sort_aggregate<<<kB, 256, 0, stream>>>(bucket_fill, records, s_h, s_t, s_r, xr, out);
}

// Round 6
// 168.415 us; speedup vs baseline: 3.5688x; 1.5201x over previous
//
#include <hip/hip_runtime.h>

static constexpr int kNE = 50000;
static constexpr int kNR = 1000;
static constexpr int kE  = 800000;
static constexpr int kEH = 256;
static constexpr int kRH = 64;
static constexpr float kNeg = 0.01f;

static constexpr int kSegs = 2 * kNE;                      // head segs then tail segs
static constexpr int kSegsPerB = 128;
static constexpr int kB = (kSegs + kSegsPerB - 1) / kSegsPerB;   // 782
static constexpr int kCap = 3072;                          // per-bucket capacity (mean 2047)
static constexpr int kEdgesPerBin = 2048;                  // records per bin block = 4096
static constexpr int kBinBlocks  = (kE + kEdgesPerBin - 1) / kEdgesPerBin;  // 391
static constexpr int kNodeBlocks = kNE / 8;                // 6250 (512 thr = 8 waves = 8 nodes)
static constexpr int kRelBlocks  = kNR / 8;                // 125

__device__ __forceinline__ float lrelu(float x){ return x > 0.f ? x : kNeg * x; }

// ---------- K2: grid-sectioned: [bin+LDS-sort+coalesced write | node scores | rel scores] ----------
__global__ __launch_bounds__(512) void k_bin_scores(
        const float* __restrict__ xe, const float* __restrict__ ahw,
        const float* __restrict__ atw, const float* __restrict__ xr,
        const float* __restrict__ arw,
        const int* __restrict__ head, const int* __restrict__ tail,
        const int* __restrict__ rel,
        float* __restrict__ s_h, float* __restrict__ s_t, float* __restrict__ s_r,
        int* __restrict__ bucket_fill, unsigned int* __restrict__ records){
    __shared__ int cnt[1024];          // padded (kB=782)
    __shared__ int start[1024];
    __shared__ int cur[1024];
    __shared__ unsigned int srt[2 * kEdgesPerBin];   // 16 KB sorted records
    __shared__ int scan_tmp[512];
    __shared__ int sh_total;

    int blk = blockIdx.x;
    int tid = threadIdx.x;
    int lane = tid & 63;

    if (blk >= kBinBlocks){
        int sb = blk - kBinBlocks;
        if (sb < kNodeBlocks){
            int node = sb * 8 + (tid >> 6);
            const float4* row = (const float4*)(xe + (size_t)node * kEH);
            float4 xv = row[lane];
            float4 av = ((const float4*)ahw)[lane];
            float4 bv = ((const float4*)atw)[lane];
            float ph = xv.x*av.x + xv.y*av.y + xv.z*av.z + xv.w*av.w;
            float pt = xv.x*bv.x + xv.y*bv.y + xv.z*bv.z + xv.w*bv.w;
            #pragma unroll
            for (int o = 32; o > 0; o >>= 1){
                ph += __shfl_down(ph, o, 64);
                pt += __shfl_down(pt, o, 64);
            }
            if (lane == 0){ s_h[node] = ph; s_t[node] = pt; }
        } else {
            int r = (sb - kNodeBlocks) * 8 + (tid >> 6);
            float p = xr[(size_t)r * kRH + lane] * arw[lane];
            #pragma unroll
            for (int o = 32; o > 0; o >>= 1) p += __shfl_down(p, o, 64);
            if (lane == 0) s_r[r] = p;
        }
        return;
    }

    // ---- bin section ----
    int e0 = blk * kEdgesPerBin;
    for (int i = tid; i < 1024; i += 512) cnt[i] = 0;
    __syncthreads();

    unsigned int recs[8];
    #pragma unroll
    for (int p = 0; p < 4; ++p){
        int e = e0 + p * 512 + tid;
        unsigned int rh = 0xFFFFFFFFu, rt = 0xFFFFFFFFu;
        if (e < kE){
            int h = head[e], t = tail[e], r = rel[e];
            rh = ((unsigned int)h << 10) | (unsigned int)r;
            rt = ((unsigned int)(kNE + t) << 10) | (unsigned int)r;
            atomicAdd(&cnt[h >> 7], 1);
            atomicAdd(&cnt[(kNE + t) >> 7], 1);
        }
        recs[p] = rh; recs[4 + p] = rt;
    }
    __syncthreads();

    // exclusive scan over cnt[1024]: thread t owns entries 2t, 2t+1
    int c0 = cnt[2 * tid], c1 = cnt[2 * tid + 1];
    int v = c0 + c1;
    scan_tmp[tid] = v;
    __syncthreads();
    for (int o = 1; o < 512; o <<= 1){
        int add = (tid >= o) ? scan_tmp[tid - o] : 0;
        __syncthreads();
        scan_tmp[tid] += add;
        __syncthreads();
    }
    int incl = scan_tmp[tid];
    int base = incl - v;
    start[2 * tid] = base;          cur[2 * tid] = base;
    start[2 * tid + 1] = base + c0; cur[2 * tid + 1] = base + c0;
    if (tid == 511) sh_total = incl;
    __syncthreads();

    // scatter into sorted LDS order
    #pragma unroll
    for (int p = 0; p < 8; ++p){
        unsigned int rc = recs[p];
        if (rc != 0xFFFFFFFFu){
            int slot = atomicAdd(&cur[rc >> 17], 1);
            srt[slot] = rc;
        }
    }
    __syncthreads();

    // reserve global runs; cur[bk] := gbase - start[bk] so gslot = cur[bk] + j
    for (int i = tid; i < kB; i += 512){
        int c = cur[i] - start[i];
        int gb = (c > 0) ? atomicAdd(&bucket_fill[i], c) : 0;
        cur[i] = gb - start[i];
    }
    __syncthreads();

    // coalesced write-out of sorted runs
    int total = sh_total;
    for (int j = tid; j < total; j += 512){
        unsigned int rc = srt[j];
        int bk = rc >> 17;
        int g  = cur[bk] + j;
        if (g < kCap) records[(size_t)bk * kCap + g] = rc;
    }
}

// ---------- K3: per-bucket LDS seg-sort + per-lane softmax + float4 group aggregate ----------
__global__ __launch_bounds__(256) void k_sort_aggregate(
        const int* __restrict__ bucket_fill, const unsigned int* __restrict__ records,
        const float* __restrict__ s_h, const float* __restrict__ s_t,
        const float* __restrict__ s_r, const float* __restrict__ xr,
        float* __restrict__ out){
    __shared__ float srl[kNR];                 // 4 KB
    __shared__ unsigned short relbuf[kCap];    // 6 KB
    __shared__ float alphabuf[kCap];           // 12 KB (logits, then exp)
    __shared__ float invbuf[kSegsPerB];
    __shared__ int cnt[kSegsPerB], start[kSegsPerB], cur[kSegsPerB], scanbuf[kSegsPerB];

    int b = blockIdx.x;
    int tid = threadIdx.x;

    for (int i = tid; i < kNR; i += 256) srl[i] = s_r[i];
    if (tid < kSegsPerB) cnt[tid] = 0;
    __syncthreads();

    int nrec = bucket_fill[b];
    if (nrec > kCap) nrec = kCap;
    const unsigned int* rb = records + (size_t)b * kCap;

    unsigned int recs[12];
    #pragma unroll
    for (int p = 0; p < 12; ++p){
        int idx = p * 256 + tid;
        unsigned int rc = 0xFFFFFFFFu;
        if (idx < nrec){
            rc = rb[idx];
            atomicAdd(&cnt[(rc >> 10) & 127], 1);
        }
        recs[p] = rc;
    }
    __syncthreads();
    if (tid < kSegsPerB) scanbuf[tid] = cnt[tid];
    __syncthreads();
    for (int o = 1; o < kSegsPerB; o <<= 1){
        int v = 0;
        if (tid < kSegsPerB && tid >= o) v = scanbuf[tid - o];
        __syncthreads();
        if (tid < kSegsPerB) scanbuf[tid] += v;
        __syncthreads();
    }
    if (tid < kSegsPerB){
        int s = scanbuf[tid] - cnt[tid];
        start[tid] = s;
        cur[tid] = s;
    }
    __syncthreads();
    #pragma unroll
    for (int p = 0; p < 12; ++p){
        unsigned int rc = recs[p];
        if (rc != 0xFFFFFFFFu){
            int slot = atomicAdd(&cur[(rc >> 10) & 127], 1);
            relbuf[slot] = (unsigned short)(rc & 1023u);
        }
    }
    __syncthreads();

    // softmax: one lane per segment, no cross-lane reductions
    if (tid < kSegsPerB){
        int gseg = b * kSegsPerB + tid;
        if (gseg < kSegs){
            int deg = cnt[tid], st = start[tid];
            float sn = (gseg < kNE) ? s_h[gseg] : s_t[gseg - kNE];
            float m = -INFINITY;
            for (int k = 0; k < deg; ++k){
                float lg = lrelu(sn + srl[relbuf[st + k]]);
                alphabuf[st + k] = lg;
                m = fmaxf(m, lg);
            }
            float ssum = 0.f;
            for (int k = 0; k < deg; ++k){
                float e = __expf(alphabuf[st + k] - m);
                alphabuf[st + k] = e;
                ssum += e;
            }
            invbuf[tid] = 1.f / (ssum + 1e-16f);
        }
    }
    __syncthreads();

    // aggregate: 16-lane group per segment, float4 per lane, unroll 4
    int grp = tid >> 4;        // 0..15
    int sub = tid & 15;        // feature quad
    for (int ls = grp; ls < kSegsPerB; ls += 16){
        int gseg = b * kSegsPerB + ls;
        if (gseg >= kSegs) break;
        int deg = cnt[ls], st = start[ls];
        float inv = invbuf[ls];
        float4 acc = {0.f, 0.f, 0.f, 0.f};
        int k = 0;
        for (; k + 4 <= deg; k += 4){
            int r0 = relbuf[st + k],     r1 = relbuf[st + k + 1];
            int r2 = relbuf[st + k + 2], r3 = relbuf[st + k + 3];
            float a0 = alphabuf[st + k] * inv,     a1 = alphabuf[st + k + 1] * inv;
            float a2 = alphabuf[st + k + 2] * inv, a3 = alphabuf[st + k + 3] * inv;
            float4 v0 = ((const float4*)(xr + (size_t)r0 * kRH))[sub];
            float4 v1 = ((const float4*)(xr + (size_t)r1 * kRH))[sub];
            float4 v2 = ((const float4*)(xr + (size_t)r2 * kRH))[sub];
            float4 v3 = ((const float4*)(xr + (size_t)r3 * kRH))[sub];
            acc.x += a0*v0.x + a1*v1.x + a2*v2.x + a3*v3.x;
            acc.y += a0*v0.y + a1*v1.y + a2*v2.y + a3*v3.y;
            acc.z += a0*v0.z + a1*v1.z + a2*v2.z + a3*v3.z;
            acc.w += a0*v0.w + a1*v1.w + a2*v2.w + a3*v3.w;
        }
        for (; k < deg; ++k){
            int rr = relbuf[st + k];
            float a = alphabuf[st + k] * inv;
            float4 v = ((const float4*)(xr + (size_t)rr * kRH))[sub];
            acc.x += a*v.x; acc.y += a*v.y; acc.z += a*v.z; acc.w += a*v.w;
        }
        bool isHead = gseg < kNE;
        int node = isHead ? gseg : gseg - kNE;
        float4* op = (float4*)(out + (size_t)node * (2 * kRH) + (isHead ? 0 : kRH));
        op[sub] = acc;
    }
}

extern "C" void kernel_launch(void* const* d_in, const int* in_sizes, int n_in,
                              void* d_out, int out_size, void* d_ws, size_t ws_size,
                              hipStream_t stream) {
    const float* xe  = (const float*)d_in[0];    // [50000,256] f32
    const float* xr  = (const float*)d_in[1];    // [1000,64]   f32
    const int* edge_index = (const int*)d_in[2]; // [2,800000]
    const int* rel        = (const int*)d_in[3]; // [800000]
    const float* ahw = (const float*)d_in[6];    // [256]
    const float* atw = (const float*)d_in[7];    // [256]
    const float* arw = (const float*)d_in[8];    // [64]
    float* out = (float*)d_out;                  // [50000,128] f32

    const int* head = edge_index;
    const int* tail = edge_index + kE;

    char* ws = (char*)d_ws;
    float* s_h  = (float*)ws;                    ws += kNE * sizeof(float);
    float* s_t  = (float*)ws;                    ws += kNE * sizeof(float);
    float* s_r  = (float*)ws;                    ws += kNR * sizeof(float);
    int*   bucket_fill = (int*)ws;               ws += kB * sizeof(int);
    unsigned int* records = (unsigned int*)ws;   ws += (size_t)kB * kCap * sizeof(unsigned int);

    hipMemsetAsync(bucket_fill, 0, kB * sizeof(int), stream);
    k_bin_scores<<<kBinBlocks + kNodeBlocks + kRelBlocks, 512, 0, stream>>>(
        xe, ahw, atw, xr, arw, head, tail, rel, s_h, s_t, s_r, bucket_fill, records);
    k_sort_aggregate<<<kB, 256, 0, stream>>>(bucket_fill, records, s_h, s_t, s_r, xr, out);
}